// Round 9
// baseline (229.332 us; speedup 1.0000x reference)
//
#include <hip/hip_runtime.h>
#include <hip/hip_bf16.h>
#include <stdint.h>

#define BATCH 4
#define SEQ   2048
#define DM    1024
#define NH    16
#define DH    64
#define MT    (BATCH*SEQ)   // 8192 rows

typedef __attribute__((ext_vector_type(8))) short  short8;
typedef __attribute__((ext_vector_type(4))) float  f32x4;

typedef const __attribute__((address_space(1))) uint32_t gu32;
typedef __attribute__((address_space(3)))       uint32_t lu32;

__device__ __forceinline__ unsigned short f2bf(float f) {
  union { float f; uint32_t u; } v; v.f = f;
  return (unsigned short)((v.u + 0x7fffu + ((v.u >> 16) & 1u)) >> 16);
}

// RNE pack of two f32 -> packed 2xbf16 (compiler fuses to v_cvt_pk_bf16_f32).
__device__ __forceinline__ uint32_t pack_bf16(float a, float b) {
  union { __hip_bfloat162 h2; uint32_t u; } v;
  v.h2.x = __float2bfloat16(a);
  v.h2.y = __float2bfloat16(b);
  return v.u;
}

__device__ __forceinline__ f32x4 mfma_bf16(short8 a, short8 b, f32x4 c) {
  asm("v_mfma_f32_16x16x32_bf16 %0, %1, %2, %0" : "+v"(c) : "v"(a), "v"(b));
  return c;
}

// ---------------- cast f32 -> bf16 (x + 4 weight matrices) ----------------
__global__ __launch_bounds__(256) void cast_all_k(
    const float* __restrict__ x,
    const float* __restrict__ wq, const float* __restrict__ wk,
    const float* __restrict__ wv, const float* __restrict__ wo,
    unsigned short* __restrict__ xb,
    unsigned short* __restrict__ wqb, unsigned short* __restrict__ wkb,
    unsigned short* __restrict__ wvb, unsigned short* __restrict__ wob) {
  const size_t NX4 = (size_t)MT * DM / 4;
  const size_t NW4 = (size_t)DM * DM / 4;
  const size_t total = NX4 + 4 * NW4;
  for (size_t i = (size_t)blockIdx.x * 256 + threadIdx.x; i < total;
       i += (size_t)gridDim.x * 256) {
    const float* src; unsigned short* dst; size_t off;
    if (i < NX4) { src = x; dst = xb; off = i; }
    else {
      size_t r = i - NX4; int s = (int)(r / NW4); off = r - (size_t)s * NW4;
      src = (s == 0) ? wq : (s == 1) ? wk : (s == 2) ? wv : wo;
      dst = (s == 0) ? wqb : (s == 1) ? wkb : (s == 2) ? wvb : wob;
    }
    float4 v = *(const float4*)(src + off * 4);
    uint32_t lo = f2bf(v.x) | ((uint32_t)f2bf(v.y) << 16);
    uint32_t hi = f2bf(v.z) | ((uint32_t)f2bf(v.w) << 16);
    uint32_t* d = (uint32_t*)(dst + off * 4);
    d[0] = lo; d[1] = hi;
  }
}

// ---------------- fused QKV GEMM -------------------------------------------
__global__ __launch_bounds__(256) void qkv_gemm_k(
    const unsigned short* __restrict__ A,
    const unsigned short* __restrict__ Wqb,
    const unsigned short* __restrict__ Wkb,
    const unsigned short* __restrict__ Wvb,
    const float* __restrict__ bq, const float* __restrict__ bk,
    const float* __restrict__ bv,
    unsigned short* __restrict__ Qo, unsigned short* __restrict__ Ko,
    unsigned short* __restrict__ Vto) {
  __shared__ unsigned short As[128 * 32];
  __shared__ unsigned short Bs[128 * 32];
  const int tid = threadIdx.x;
  const int w = tid >> 6, lane = tid & 63;
  const int l15 = lane & 15, g = lane >> 4;
  const int wr = w >> 1, wc = w & 1;
  const int tm = blockIdx.x & 63;
  const int t  = blockIdx.x >> 6;        // 0..23
  const int which = t >> 3;              // 0=Q 1=K 2=V
  const int tn = t & 7;
  const int m0 = tm << 7, n0 = tn << 7;

  const unsigned short* Bw = (which == 0) ? Wqb : (which == 1) ? Wkb : Wvb;
  const float* bias = (which == 0) ? bq : (which == 1) ? bk : bv;
  const float scale = (which == 0) ? (0.125f * 1.44269504088896f) : 1.0f;

  f32x4 acc[4][4];
  const f32x4 fz = {0.f, 0.f, 0.f, 0.f};
#pragma unroll
  for (int i = 0; i < 4; ++i)
#pragma unroll
    for (int j = 0; j < 4; ++j) acc[i][j] = fz;

  const int srow = lane >> 2;
  const int scol = (lane & 3) << 3;

  for (int kt = 0; kt < 32; ++kt) {
    const int k0 = kt << 5;
    __syncthreads();
#pragma unroll
    for (int c = 0; c < 2; ++c) {
      const int chunk = (w << 1) + c;
      const int row = (chunk << 4) + srow;
      __builtin_amdgcn_global_load_lds(
          (gu32*)(A + (size_t)(m0 + row) * DM + k0 + scol),
          (lu32*)(&As[chunk << 9]), 16, 0, 0);
      __builtin_amdgcn_global_load_lds(
          (gu32*)(Bw + (size_t)(n0 + row) * DM + k0 + scol),
          (lu32*)(&Bs[chunk << 9]), 16, 0, 0);
    }
    __syncthreads();
    short8 afr[4], bfr[4];
#pragma unroll
    for (int mf = 0; mf < 4; ++mf)
      afr[mf] = *(const short8*)&As[(((wr << 6) + (mf << 4) + l15) << 5) + (g << 3)];
#pragma unroll
    for (int nf = 0; nf < 4; ++nf)
      bfr[nf] = *(const short8*)&Bs[(((wc << 6) + (nf << 4) + l15) << 5) + (g << 3)];
#pragma unroll
    for (int mf = 0; mf < 4; ++mf)
#pragma unroll
      for (int nf = 0; nf < 4; ++nf)
        acc[mf][nf] = mfma_bf16(afr[mf], bfr[nf], acc[mf][nf]);
  }

#pragma unroll
  for (int nf = 0; nf < 4; ++nf) {
    const int n = n0 + (wc << 6) + (nf << 4) + l15;
    const float bv_ = bias[n];
    const int h = n >> 6, d = n & 63;
    if (which != 2) {
      unsigned short* O = (which == 0) ? Qo : Ko;
#pragma unroll
      for (int mf = 0; mf < 4; ++mf)
#pragma unroll
        for (int r = 0; r < 4; ++r) {
          const int m = m0 + (wr << 6) + (mf << 4) + (g << 2) + r;
          const int b = m >> 11, s = m & 2047;
          O[(((size_t)(b * NH + h)) * SEQ + s) * DH + d] =
              f2bf((acc[mf][nf][r] + bv_) * scale);
        }
    } else {
#pragma unroll
      for (int mf = 0; mf < 4; ++mf) {
        const int m = m0 + (wr << 6) + (mf << 4) + (g << 2);
        const int b = m >> 11, s = m & 2047;
        const float v0 = acc[mf][nf][0] + bv_, v1 = acc[mf][nf][1] + bv_;
        const float v2 = acc[mf][nf][2] + bv_, v3 = acc[mf][nf][3] + bv_;
        uint32_t lo = pack_bf16(v0, v1);
        uint32_t hi = pack_bf16(v2, v3);
        uint32_t* dst = (uint32_t*)(Vto + (((size_t)(b * NH + h)) * DH + d) * SEQ + s);
        dst[0] = lo; dst[1] = hi;
      }
    }
  }
}

// ---------------- O-projection GEMM (f32 out) ------------------------------
__global__ __launch_bounds__(256) void gemm_o_k(
    const unsigned short* __restrict__ A,
    const unsigned short* __restrict__ Bw,
    const float* __restrict__ bias,
    float* __restrict__ out) {
  __shared__ unsigned short As[128 * 32];
  __shared__ unsigned short Bs[128 * 32];
  const int tid = threadIdx.x;
  const int w = tid >> 6, lane = tid & 63;
  const int l15 = lane & 15, g = lane >> 4;
  const int wr = w >> 1, wc = w & 1;
  const int tm = blockIdx.x & 63, tn = blockIdx.x >> 6;
  const int m0 = tm << 7, n0 = tn << 7;

  f32x4 acc[4][4];
  const f32x4 fz = {0.f, 0.f, 0.f, 0.f};
#pragma unroll
  for (int i = 0; i < 4; ++i)
#pragma unroll
    for (int j = 0; j < 4; ++j) acc[i][j] = fz;

  const int srow = lane >> 2;
  const int scol = (lane & 3) << 3;

  for (int kt = 0; kt < 32; ++kt) {
    const int k0 = kt << 5;
    __syncthreads();
#pragma unroll
    for (int c = 0; c < 2; ++c) {
      const int chunk = (w << 1) + c;
      const int row = (chunk << 4) + srow;
      __builtin_amdgcn_global_load_lds(
          (gu32*)(A + (size_t)(m0 + row) * DM + k0 + scol),
          (lu32*)(&As[chunk << 9]), 16, 0, 0);
      __builtin_amdgcn_global_load_lds(
          (gu32*)(Bw + (size_t)(n0 + row) * DM + k0 + scol),
          (lu32*)(&Bs[chunk << 9]), 16, 0, 0);
    }
    __syncthreads();
    short8 afr[4], bfr[4];
#pragma unroll
    for (int mf = 0; mf < 4; ++mf)
      afr[mf] = *(const short8*)&As[(((wr << 6) + (mf << 4) + l15) << 5) + (g << 3)];
#pragma unroll
    for (int nf = 0; nf < 4; ++nf)
      bfr[nf] = *(const short8*)&Bs[(((wc << 6) + (nf << 4) + l15) << 5) + (g << 3)];
#pragma unroll
    for (int mf = 0; mf < 4; ++mf)
#pragma unroll
      for (int nf = 0; nf < 4; ++nf)
        acc[mf][nf] = mfma_bf16(afr[mf], bfr[nf], acc[mf][nf]);
  }

#pragma unroll
  for (int nf = 0; nf < 4; ++nf) {
    const int n = n0 + (wc << 6) + (nf << 4) + l15;
    const float bv = bias[n];
#pragma unroll
    for (int mf = 0; mf < 4; ++mf)
#pragma unroll
      for (int r = 0; r < 4; ++r) {
        const int m = m0 + (wr << 6) + (mf << 4) + (g << 2) + r;
        out[(size_t)m * DM + n] = acc[mf][nf][r] + bv;
      }
  }
}

// ---------------- flash attention v5 ---------------------------------------
// R6-passing kernel with ONE structural change: V single-buffered (staged at
// the top of each iteration, overlapped with QK^T+softmax; mid-iteration
// __syncthreads makes it visible before PV; end barrier protects the buffer).
// LDS 48->40KB => __launch_bounds__(256,4), 4 blocks/CU, zero-tail grid.
// P layout, softmax, VALU l-sum, epilogue are VERBATIM R6.
__global__ __launch_bounds__(256, 4) void attn_k(
    const unsigned short* __restrict__ Q,
    const unsigned short* __restrict__ K,
    const unsigned short* __restrict__ Vt,
    unsigned short* __restrict__ Ctx) {   // [B][S][1024] bf16
  __shared__ unsigned short Kbuf[2][64 * 64];   // 16 KB (double)
  __shared__ unsigned short Vbuf[64 * 64];      // 8 KB  (single, [d][kv])
  __shared__ unsigned short Pw4[4][32 * 64];    // 16 KB (per-wave P)
  const int bh = blockIdx.x >> 4;
  const int qt = blockIdx.x & 15;
  const int b = bh >> 4, h = bh & 15;
  const unsigned short* Qb  = Q  + ((size_t)bh * SEQ + (qt << 7)) * DH;
  const unsigned short* Kb  = K  + (size_t)bh * SEQ * DH;
  const unsigned short* Vtb = Vt + (size_t)bh * DH * SEQ;
  const int tid = threadIdx.x, w = tid >> 6, lane = tid & 63;
  const int l15 = lane & 15, g = lane >> 4;
  const int s7 = l15 & 7;
  const int r8 = lane >> 3, c8 = (lane & 7) ^ r8;

  // ---- Q fragments in registers (32 q rows per wave) ----
  short8 qfr[2][2];
#pragma unroll
  for (int qh = 0; qh < 2; ++qh)
#pragma unroll
    for (int ks = 0; ks < 2; ++ks)
      qfr[qh][ks] = *(const short8*)(Qb + (size_t)((w << 5) + (qh << 4) + l15) * DH
                                        + (ks << 5) + (g << 3));

  auto stage_K = [&](int bb, int t) {
#pragma unroll
    for (int j = 0; j < 2; ++j) {
      const int row = (w << 4) + (j << 3) + r8;
      __builtin_amdgcn_global_load_lds(
          (gu32*)(Kb + ((size_t)((t << 6) + row) << 6) + (c8 << 3)),
          (lu32*)(&Kbuf[bb][((w << 4) + (j << 3)) << 6]), 16, 0, 0);
    }
  };
  auto stage_V = [&](int t) {
#pragma unroll
    for (int j = 0; j < 2; ++j) {
      const int row = (w << 4) + (j << 3) + r8;
      __builtin_amdgcn_global_load_lds(
          (gu32*)(Vtb + (size_t)row * SEQ + (t << 6) + (c8 << 3)),
          (lu32*)(&Vbuf[((w << 4) + (j << 3)) << 6]), 16, 0, 0);
    }
  };

  float l0 = 0.f, l1 = 0.f;
  const f32x4 fz = {0.f, 0.f, 0.f, 0.f};
  f32x4 accc[2][4];
#pragma unroll
  for (int qh = 0; qh < 2; ++qh)
#pragma unroll
    for (int nf = 0; nf < 4; ++nf) accc[qh][nf] = fz;
  unsigned short* PW = Pw4[w];

  stage_K(0, 0);
  asm volatile("s_waitcnt vmcnt(0)" ::: "memory");
  __syncthreads();

  for (int kt = 0; kt < 32; ++kt) {
    const int cur = kt & 1;
    stage_V(kt);                               // V[kt] -> Vbuf (single)
    if (kt < 31) stage_K(cur ^ 1, kt + 1);     // K[kt+1] -> other K buffer
    const unsigned short* KB = Kbuf[cur];

    // ---- S^T = K * Q^T  (sacc is tv directly; Q pre-scaled) ----
    f32x4 sacc[2][4];
#pragma unroll
    for (int qh = 0; qh < 2; ++qh)
#pragma unroll
      for (int mf = 0; mf < 4; ++mf) sacc[qh][mf] = fz;
    __builtin_amdgcn_s_setprio(1);
#pragma unroll
    for (int ks = 0; ks < 2; ++ks) {
      short8 kfr[4];
#pragma unroll
      for (int mf = 0; mf < 4; ++mf)
        kfr[mf] = *(const short8*)&KB[(((mf << 4) + l15) << 6)
                                      + ((((ks << 2) + g) ^ s7) << 3)];
#pragma unroll
      for (int qh = 0; qh < 2; ++qh)
#pragma unroll
        for (int mf = 0; mf < 4; ++mf)
          sacc[qh][mf] = mfma_bf16(kfr[mf], qfr[qh][ks], sacc[qh][mf]);
    }
    __builtin_amdgcn_s_setprio(0);

    // ---- shift-free softmax: p = exp2(tv), accumulate l per-lane ----
    uint32_t pw[2][4][2];
#pragma unroll
    for (int mf = 0; mf < 4; ++mf) {
      {
        const float p0 = exp2f(sacc[0][mf][0]);
        const float p1 = exp2f(sacc[0][mf][1]);
        const float p2 = exp2f(sacc[0][mf][2]);
        const float p3 = exp2f(sacc[0][mf][3]);
        l0 += (p0 + p1) + (p2 + p3);
        pw[0][mf][0] = pack_bf16(p0, p1);
        pw[0][mf][1] = pack_bf16(p2, p3);
      }
      {
        const float p0 = exp2f(sacc[1][mf][0]);
        const float p1 = exp2f(sacc[1][mf][1]);
        const float p2 = exp2f(sacc[1][mf][2]);
        const float p3 = exp2f(sacc[1][mf][3]);
        l1 += (p0 + p1) + (p2 + p3);
        pw[1][mf][0] = pack_bf16(p0, p1);
        pw[1][mf][1] = pack_bf16(p2, p3);
      }
    }

    // ---- P -> per-wave swizzled LDS (verbatim R6) ----
#pragma unroll
    for (int qh = 0; qh < 2; ++qh)
#pragma unroll
      for (int mf = 0; mf < 4; ++mf) {
        const int cc = ((mf << 1) + (g >> 1)) ^ s7;
        uint32_t* pd = (uint32_t*)&PW[(((qh << 4) + l15) << 6) + (cc << 3) + ((g & 1) << 2)];
        pd[0] = pw[qh][mf][0]; pd[1] = pw[qh][mf][1];
      }

    __syncthreads();   // drains V[kt] (+K[kt+1]); all waves' V now resident

    // ---- PV (verbatim R6, single Vbuf) ----
    __builtin_amdgcn_s_setprio(1);
#pragma unroll
    for (int ks = 0; ks < 2; ++ks) {
      short8 pfr[2], vfr[4];
#pragma unroll
      for (int qh = 0; qh < 2; ++qh)
        pfr[qh] = *(const short8*)&PW[(((qh << 4) + l15) << 6)
                                      + ((((ks << 2) + g) ^ s7) << 3)];
#pragma unroll
      for (int nf = 0; nf < 4; ++nf)
        vfr[nf] = *(const short8*)&Vbuf[(((nf << 4) + l15) << 6)
                                        + ((((ks << 2) + g) ^ s7) << 3)];
#pragma unroll
      for (int qh = 0; qh < 2; ++qh)
#pragma unroll
        for (int nf = 0; nf < 4; ++nf)
          accc[qh][nf] = mfma_bf16(pfr[qh], vfr[nf], accc[qh][nf]);
    }
    __builtin_amdgcn_s_setprio(0);

    __syncthreads();   // all waves done reading Vbuf before next stage_V
  }

  // ---- final l reduce across g-groups (lanes sharing l15) ----
  l0 += __shfl_xor(l0, 16, 64);
  l0 += __shfl_xor(l0, 32, 64);
  l1 += __shfl_xor(l1, 16, 64);
  l1 += __shfl_xor(l1, 32, 64);

  // ---- epilogue (verbatim R6) ----
  unsigned short* Cb = Ctx + ((size_t)b * SEQ + (qt << 7)) * DM + h * DH;
#pragma unroll
  for (int qh = 0; qh < 2; ++qh) {
    const float linv = 1.0f / ((qh == 0) ? l0 : l1);
    float lr[4];
#pragma unroll
    for (int r = 0; r < 4; ++r) lr[r] = __shfl(linv, (g << 2) + r, 64);
#pragma unroll
    for (int nf = 0; nf < 4; ++nf) {
      const int d = (nf << 4) + l15;
#pragma unroll
      for (int r = 0; r < 4; ++r) {
        const int q = (w << 5) + (qh << 4) + (g << 2) + r;
        Cb[(size_t)q * DM + d] = f2bf(accc[qh][nf][r] * lr[r]);
      }
    }
  }
}

// ---------------------------------------------------------------------------
extern "C" void kernel_launch(void* const* d_in, const int* in_sizes, int n_in,
                              void* d_out, int out_size, void* d_ws, size_t ws_size,
                              hipStream_t stream) {
  const float* x  = (const float*)d_in[0];
  const float* Wq = (const float*)d_in[1];
  const float* bq = (const float*)d_in[2];
  const float* Wk = (const float*)d_in[3];
  const float* bk = (const float*)d_in[4];
  const float* Wv = (const float*)d_in[5];
  const float* bv = (const float*)d_in[6];
  const float* Wo = (const float*)d_in[7];
  const float* bo = (const float*)d_in[8];

  char* ws = (char*)d_ws;
  size_t off = 0;
  auto alloc = [&](size_t bytes) -> void* {
    void* p = ws + off;
    off += (bytes + 255) & ~(size_t)255;
    return p;
  };
  const size_t XB = (size_t)MT * DM * 2;   // 16.78 MB
  const size_t WB = (size_t)DM * DM * 2;   // 2.10 MB
  unsigned short* Xb  = (unsigned short*)alloc(XB);
  unsigned short* Wqb = (unsigned short*)alloc(WB);
  unsigned short* Wkb = (unsigned short*)alloc(WB);
  unsigned short* Wvb = (unsigned short*)alloc(WB);
  unsigned short* Wob = (unsigned short*)alloc(WB);
  unsigned short* Qb  = (unsigned short*)alloc(XB);
  unsigned short* Kb  = (unsigned short*)alloc(XB);
  unsigned short* Vtb = (unsigned short*)alloc(XB);
  unsigned short* Cxb = (unsigned short*)alloc(XB);

  cast_all_k<<<dim3(1024), dim3(256), 0, stream>>>(
      x, Wq, Wk, Wv, Wo, Xb, Wqb, Wkb, Wvb, Wob);
  qkv_gemm_k<<<dim3(1536), dim3(256), 0, stream>>>(
      Xb, Wqb, Wkb, Wvb, bq, bk, bv, Qb, Kb, Vtb);
  attn_k<<<dim3(1024), dim3(256), 0, stream>>>(Qb, Kb, Vtb, Cxb);
  gemm_o_k<<<dim3(512), dim3(256), 0, stream>>>(Cxb, Wob, bo, (float*)d_out);
}

// Round 10
// 223.480 us; speedup vs baseline: 1.0262x; 1.0262x over previous
//
#include <hip/hip_runtime.h>
#include <hip/hip_bf16.h>
#include <stdint.h>

#define BATCH 4
#define SEQ   2048
#define DM    1024
#define NH    16
#define DH    64
#define MT    (BATCH*SEQ)   // 8192 rows

typedef __attribute__((ext_vector_type(8))) short  short8;
typedef __attribute__((ext_vector_type(4))) float  f32x4;

typedef const __attribute__((address_space(1))) uint32_t gu32;
typedef __attribute__((address_space(3)))       uint32_t lu32;

__device__ __forceinline__ unsigned short f2bf(float f) {
  union { float f; uint32_t u; } v; v.f = f;
  return (unsigned short)((v.u + 0x7fffu + ((v.u >> 16) & 1u)) >> 16);
}

// RNE pack of two f32 -> packed 2xbf16 (compiler fuses to v_cvt_pk_bf16_f32).
__device__ __forceinline__ uint32_t pack_bf16(float a, float b) {
  union { __hip_bfloat162 h2; uint32_t u; } v;
  v.h2.x = __float2bfloat16(a);
  v.h2.y = __float2bfloat16(b);
  return v.u;
}

__device__ __forceinline__ f32x4 mfma_bf16(short8 a, short8 b, f32x4 c) {
  asm("v_mfma_f32_16x16x32_bf16 %0, %1, %2, %0" : "+v"(c) : "v"(a), "v"(b));
  return c;
}

// ---------------- cast f32 -> bf16 (x + 4 weight matrices) ----------------
__global__ __launch_bounds__(256) void cast_all_k(
    const float* __restrict__ x,
    const float* __restrict__ wq, const float* __restrict__ wk,
    const float* __restrict__ wv, const float* __restrict__ wo,
    unsigned short* __restrict__ xb,
    unsigned short* __restrict__ wqb, unsigned short* __restrict__ wkb,
    unsigned short* __restrict__ wvb, unsigned short* __restrict__ wob) {
  const size_t NX4 = (size_t)MT * DM / 4;
  const size_t NW4 = (size_t)DM * DM / 4;
  const size_t total = NX4 + 4 * NW4;
  for (size_t i = (size_t)blockIdx.x * 256 + threadIdx.x; i < total;
       i += (size_t)gridDim.x * 256) {
    const float* src; unsigned short* dst; size_t off;
    if (i < NX4) { src = x; dst = xb; off = i; }
    else {
      size_t r = i - NX4; int s = (int)(r / NW4); off = r - (size_t)s * NW4;
      src = (s == 0) ? wq : (s == 1) ? wk : (s == 2) ? wv : wo;
      dst = (s == 0) ? wqb : (s == 1) ? wkb : (s == 2) ? wvb : wob;
    }
    float4 v = *(const float4*)(src + off * 4);
    uint32_t lo = f2bf(v.x) | ((uint32_t)f2bf(v.y) << 16);
    uint32_t hi = f2bf(v.z) | ((uint32_t)f2bf(v.w) << 16);
    uint32_t* d = (uint32_t*)(dst + off * 4);
    d[0] = lo; d[1] = hi;
  }
}

// ---------------- fused QKV GEMM -------------------------------------------
__global__ __launch_bounds__(256) void qkv_gemm_k(
    const unsigned short* __restrict__ A,
    const unsigned short* __restrict__ Wqb,
    const unsigned short* __restrict__ Wkb,
    const unsigned short* __restrict__ Wvb,
    const float* __restrict__ bq, const float* __restrict__ bk,
    const float* __restrict__ bv,
    unsigned short* __restrict__ Qo, unsigned short* __restrict__ Ko,
    unsigned short* __restrict__ Vto) {
  __shared__ unsigned short As[128 * 32];
  __shared__ unsigned short Bs[128 * 32];
  const int tid = threadIdx.x;
  const int w = tid >> 6, lane = tid & 63;
  const int l15 = lane & 15, g = lane >> 4;
  const int wr = w >> 1, wc = w & 1;
  const int tm = blockIdx.x & 63;
  const int t  = blockIdx.x >> 6;        // 0..23
  const int which = t >> 3;              // 0=Q 1=K 2=V
  const int tn = t & 7;
  const int m0 = tm << 7, n0 = tn << 7;

  const unsigned short* Bw = (which == 0) ? Wqb : (which == 1) ? Wkb : Wvb;
  const float* bias = (which == 0) ? bq : (which == 1) ? bk : bv;
  const float scale = (which == 0) ? (0.125f * 1.44269504088896f) : 1.0f;

  f32x4 acc[4][4];
  const f32x4 fz = {0.f, 0.f, 0.f, 0.f};
#pragma unroll
  for (int i = 0; i < 4; ++i)
#pragma unroll
    for (int j = 0; j < 4; ++j) acc[i][j] = fz;

  const int srow = lane >> 2;
  const int scol = (lane & 3) << 3;

  for (int kt = 0; kt < 32; ++kt) {
    const int k0 = kt << 5;
    __syncthreads();
#pragma unroll
    for (int c = 0; c < 2; ++c) {
      const int chunk = (w << 1) + c;
      const int row = (chunk << 4) + srow;
      __builtin_amdgcn_global_load_lds(
          (gu32*)(A + (size_t)(m0 + row) * DM + k0 + scol),
          (lu32*)(&As[chunk << 9]), 16, 0, 0);
      __builtin_amdgcn_global_load_lds(
          (gu32*)(Bw + (size_t)(n0 + row) * DM + k0 + scol),
          (lu32*)(&Bs[chunk << 9]), 16, 0, 0);
    }
    __syncthreads();
    short8 afr[4], bfr[4];
#pragma unroll
    for (int mf = 0; mf < 4; ++mf)
      afr[mf] = *(const short8*)&As[(((wr << 6) + (mf << 4) + l15) << 5) + (g << 3)];
#pragma unroll
    for (int nf = 0; nf < 4; ++nf)
      bfr[nf] = *(const short8*)&Bs[(((wc << 6) + (nf << 4) + l15) << 5) + (g << 3)];
#pragma unroll
    for (int mf = 0; mf < 4; ++mf)
#pragma unroll
      for (int nf = 0; nf < 4; ++nf)
        acc[mf][nf] = mfma_bf16(afr[mf], bfr[nf], acc[mf][nf]);
  }

#pragma unroll
  for (int nf = 0; nf < 4; ++nf) {
    const int n = n0 + (wc << 6) + (nf << 4) + l15;
    const float bv_ = bias[n];
    const int h = n >> 6, d = n & 63;
    if (which != 2) {
      unsigned short* O = (which == 0) ? Qo : Ko;
#pragma unroll
      for (int mf = 0; mf < 4; ++mf)
#pragma unroll
        for (int r = 0; r < 4; ++r) {
          const int m = m0 + (wr << 6) + (mf << 4) + (g << 2) + r;
          const int b = m >> 11, s = m & 2047;
          O[(((size_t)(b * NH + h)) * SEQ + s) * DH + d] =
              f2bf((acc[mf][nf][r] + bv_) * scale);
        }
    } else {
#pragma unroll
      for (int mf = 0; mf < 4; ++mf) {
        const int m = m0 + (wr << 6) + (mf << 4) + (g << 2);
        const int b = m >> 11, s = m & 2047;
        const float v0 = acc[mf][nf][0] + bv_, v1 = acc[mf][nf][1] + bv_;
        const float v2 = acc[mf][nf][2] + bv_, v3 = acc[mf][nf][3] + bv_;
        uint32_t lo = pack_bf16(v0, v1);
        uint32_t hi = pack_bf16(v2, v3);
        uint32_t* dst = (uint32_t*)(Vto + (((size_t)(b * NH + h)) * DH + d) * SEQ + s);
        dst[0] = lo; dst[1] = hi;
      }
    }
  }
}

// ---------------- O-projection GEMM (f32 out) ------------------------------
__global__ __launch_bounds__(256) void gemm_o_k(
    const unsigned short* __restrict__ A,
    const unsigned short* __restrict__ Bw,
    const float* __restrict__ bias,
    float* __restrict__ out) {
  __shared__ unsigned short As[128 * 32];
  __shared__ unsigned short Bs[128 * 32];
  const int tid = threadIdx.x;
  const int w = tid >> 6, lane = tid & 63;
  const int l15 = lane & 15, g = lane >> 4;
  const int wr = w >> 1, wc = w & 1;
  const int tm = blockIdx.x & 63, tn = blockIdx.x >> 6;
  const int m0 = tm << 7, n0 = tn << 7;

  f32x4 acc[4][4];
  const f32x4 fz = {0.f, 0.f, 0.f, 0.f};
#pragma unroll
  for (int i = 0; i < 4; ++i)
#pragma unroll
    for (int j = 0; j < 4; ++j) acc[i][j] = fz;

  const int srow = lane >> 2;
  const int scol = (lane & 3) << 3;

  for (int kt = 0; kt < 32; ++kt) {
    const int k0 = kt << 5;
    __syncthreads();
#pragma unroll
    for (int c = 0; c < 2; ++c) {
      const int chunk = (w << 1) + c;
      const int row = (chunk << 4) + srow;
      __builtin_amdgcn_global_load_lds(
          (gu32*)(A + (size_t)(m0 + row) * DM + k0 + scol),
          (lu32*)(&As[chunk << 9]), 16, 0, 0);
      __builtin_amdgcn_global_load_lds(
          (gu32*)(Bw + (size_t)(n0 + row) * DM + k0 + scol),
          (lu32*)(&Bs[chunk << 9]), 16, 0, 0);
    }
    __syncthreads();
    short8 afr[4], bfr[4];
#pragma unroll
    for (int mf = 0; mf < 4; ++mf)
      afr[mf] = *(const short8*)&As[(((wr << 6) + (mf << 4) + l15) << 5) + (g << 3)];
#pragma unroll
    for (int nf = 0; nf < 4; ++nf)
      bfr[nf] = *(const short8*)&Bs[(((wc << 6) + (nf << 4) + l15) << 5) + (g << 3)];
#pragma unroll
    for (int mf = 0; mf < 4; ++mf)
#pragma unroll
      for (int nf = 0; nf < 4; ++nf)
        acc[mf][nf] = mfma_bf16(afr[mf], bfr[nf], acc[mf][nf]);
  }

#pragma unroll
  for (int nf = 0; nf < 4; ++nf) {
    const int n = n0 + (wc << 6) + (nf << 4) + l15;
    const float bv = bias[n];
#pragma unroll
    for (int mf = 0; mf < 4; ++mf)
#pragma unroll
      for (int r = 0; r < 4; ++r) {
        const int m = m0 + (wr << 6) + (mf << 4) + (g << 2) + r;
        out[(size_t)m * DM + n] = acc[mf][nf][r] + bv;
      }
  }
}

// ---------------- flash attention v6 ---------------------------------------
// R9 structure with counted-vmcnt raw barriers (T4):
//   stage V (2 loads) -> sched_barrier -> stage K[kt+1] (2 loads)
//   mid:  s_waitcnt vmcnt(2)  (own V done; K prefetch stays in flight)
//   end:  s_waitcnt vmcnt(0)  (K drained once, after full-iteration window)
// Raw s_barrier (no auto vmcnt(0)/lgkmcnt(0) drain). Each wave drains its own
// staged share before the shared barrier => tiles coherent after it, same
// guarantee as __syncthreads without the over-drain. P stays wave-private.
// Last iteration: only V outstanding => mid wait must be vmcnt(0).
__global__ __launch_bounds__(256, 4) void attn_k(
    const unsigned short* __restrict__ Q,
    const unsigned short* __restrict__ K,
    const unsigned short* __restrict__ Vt,
    unsigned short* __restrict__ Ctx) {   // [B][S][1024] bf16
  __shared__ unsigned short Kbuf[2][64 * 64];   // 16 KB (double)
  __shared__ unsigned short Vbuf[64 * 64];      // 8 KB  (single, [d][kv])
  __shared__ unsigned short Pw4[4][32 * 64];    // 16 KB (per-wave P)
  const int bh = blockIdx.x >> 4;
  const int qt = blockIdx.x & 15;
  const int b = bh >> 4, h = bh & 15;
  const unsigned short* Qb  = Q  + ((size_t)bh * SEQ + (qt << 7)) * DH;
  const unsigned short* Kb  = K  + (size_t)bh * SEQ * DH;
  const unsigned short* Vtb = Vt + (size_t)bh * DH * SEQ;
  const int tid = threadIdx.x, w = tid >> 6, lane = tid & 63;
  const int l15 = lane & 15, g = lane >> 4;
  const int s7 = l15 & 7;
  const int r8 = lane >> 3, c8 = (lane & 7) ^ r8;

  // ---- Q fragments in registers (32 q rows per wave) ----
  short8 qfr[2][2];
#pragma unroll
  for (int qh = 0; qh < 2; ++qh)
#pragma unroll
    for (int ks = 0; ks < 2; ++ks)
      qfr[qh][ks] = *(const short8*)(Qb + (size_t)((w << 5) + (qh << 4) + l15) * DH
                                        + (ks << 5) + (g << 3));

  auto stage_K = [&](int bb, int t) {
#pragma unroll
    for (int j = 0; j < 2; ++j) {
      const int row = (w << 4) + (j << 3) + r8;
      __builtin_amdgcn_global_load_lds(
          (gu32*)(Kb + ((size_t)((t << 6) + row) << 6) + (c8 << 3)),
          (lu32*)(&Kbuf[bb][((w << 4) + (j << 3)) << 6]), 16, 0, 0);
    }
  };
  auto stage_V = [&](int t) {
#pragma unroll
    for (int j = 0; j < 2; ++j) {
      const int row = (w << 4) + (j << 3) + r8;
      __builtin_amdgcn_global_load_lds(
          (gu32*)(Vtb + (size_t)row * SEQ + (t << 6) + (c8 << 3)),
          (lu32*)(&Vbuf[((w << 4) + (j << 3)) << 6]), 16, 0, 0);
    }
  };

  float l0 = 0.f, l1 = 0.f;
  const f32x4 fz = {0.f, 0.f, 0.f, 0.f};
  f32x4 accc[2][4];
#pragma unroll
  for (int qh = 0; qh < 2; ++qh)
#pragma unroll
    for (int nf = 0; nf < 4; ++nf) accc[qh][nf] = fz;
  unsigned short* PW = Pw4[w];

  stage_K(0, 0);
  asm volatile("s_waitcnt vmcnt(0)" ::: "memory");
  __builtin_amdgcn_s_barrier();

  for (int kt = 0; kt < 32; ++kt) {
    const int cur = kt & 1;
    stage_V(kt);                               // 2 loads (oldest)
    __builtin_amdgcn_sched_barrier(0);         // pin V-before-K issue order
    if (kt < 31) stage_K(cur ^ 1, kt + 1);     // 2 loads (newest)
    const unsigned short* KB = Kbuf[cur];

    // ---- S^T = K * Q^T  (sacc is tv directly; Q pre-scaled) ----
    f32x4 sacc[2][4];
#pragma unroll
    for (int qh = 0; qh < 2; ++qh)
#pragma unroll
      for (int mf = 0; mf < 4; ++mf) sacc[qh][mf] = fz;
    __builtin_amdgcn_s_setprio(1);
#pragma unroll
    for (int ks = 0; ks < 2; ++ks) {
      short8 kfr[4];
#pragma unroll
      for (int mf = 0; mf < 4; ++mf)
        kfr[mf] = *(const short8*)&KB[(((mf << 4) + l15) << 6)
                                      + ((((ks << 2) + g) ^ s7) << 3)];
#pragma unroll
      for (int qh = 0; qh < 2; ++qh)
#pragma unroll
        for (int mf = 0; mf < 4; ++mf)
          sacc[qh][mf] = mfma_bf16(kfr[mf], qfr[qh][ks], sacc[qh][mf]);
    }
    __builtin_amdgcn_s_setprio(0);

    // ---- shift-free softmax: p = exp2(tv), accumulate l per-lane ----
    uint32_t pw[2][4][2];
#pragma unroll
    for (int mf = 0; mf < 4; ++mf) {
      {
        const float p0 = exp2f(sacc[0][mf][0]);
        const float p1 = exp2f(sacc[0][mf][1]);
        const float p2 = exp2f(sacc[0][mf][2]);
        const float p3 = exp2f(sacc[0][mf][3]);
        l0 += (p0 + p1) + (p2 + p3);
        pw[0][mf][0] = pack_bf16(p0, p1);
        pw[0][mf][1] = pack_bf16(p2, p3);
      }
      {
        const float p0 = exp2f(sacc[1][mf][0]);
        const float p1 = exp2f(sacc[1][mf][1]);
        const float p2 = exp2f(sacc[1][mf][2]);
        const float p3 = exp2f(sacc[1][mf][3]);
        l1 += (p0 + p1) + (p2 + p3);
        pw[1][mf][0] = pack_bf16(p0, p1);
        pw[1][mf][1] = pack_bf16(p2, p3);
      }
    }

    // ---- P -> per-wave swizzled LDS ----
#pragma unroll
    for (int qh = 0; qh < 2; ++qh)
#pragma unroll
      for (int mf = 0; mf < 4; ++mf) {
        const int cc = ((mf << 1) + (g >> 1)) ^ s7;
        uint32_t* pd = (uint32_t*)&PW[(((qh << 4) + l15) << 6) + (cc << 3) + ((g & 1) << 2)];
        pd[0] = pw[qh][mf][0]; pd[1] = pw[qh][mf][1];
      }

    // ---- mid barrier: wait own V only (K[kt+1] stays in flight) ----
    if (kt < 31) {
      asm volatile("s_waitcnt vmcnt(2)" ::: "memory");
    } else {
      asm volatile("s_waitcnt vmcnt(0)" ::: "memory");
    }
    __builtin_amdgcn_s_barrier();

    // ---- PV (single Vbuf) ----
    __builtin_amdgcn_s_setprio(1);
#pragma unroll
    for (int ks = 0; ks < 2; ++ks) {
      short8 pfr[2], vfr[4];
#pragma unroll
      for (int qh = 0; qh < 2; ++qh)
        pfr[qh] = *(const short8*)&PW[(((qh << 4) + l15) << 6)
                                      + ((((ks << 2) + g) ^ s7) << 3)];
#pragma unroll
      for (int nf = 0; nf < 4; ++nf)
        vfr[nf] = *(const short8*)&Vbuf[(((nf << 4) + l15) << 6)
                                        + ((((ks << 2) + g) ^ s7) << 3)];
#pragma unroll
      for (int qh = 0; qh < 2; ++qh)
#pragma unroll
        for (int nf = 0; nf < 4; ++nf)
          accc[qh][nf] = mfma_bf16(pfr[qh], vfr[nf], accc[qh][nf]);
    }
    __builtin_amdgcn_s_setprio(0);

    // ---- end barrier: drain K[kt+1]; Vbuf free for next overwrite ----
    asm volatile("s_waitcnt vmcnt(0)" ::: "memory");
    __builtin_amdgcn_s_barrier();
  }

  // ---- final l reduce across g-groups (lanes sharing l15) ----
  l0 += __shfl_xor(l0, 16, 64);
  l0 += __shfl_xor(l0, 32, 64);
  l1 += __shfl_xor(l1, 16, 64);
  l1 += __shfl_xor(l1, 32, 64);

  // ---- epilogue ----
  unsigned short* Cb = Ctx + ((size_t)b * SEQ + (qt << 7)) * DM + h * DH;
#pragma unroll
  for (int qh = 0; qh < 2; ++qh) {
    const float linv = 1.0f / ((qh == 0) ? l0 : l1);
    float lr[4];
#pragma unroll
    for (int r = 0; r < 4; ++r) lr[r] = __shfl(linv, (g << 2) + r, 64);
#pragma unroll
    for (int nf = 0; nf < 4; ++nf) {
      const int d = (nf << 4) + l15;
#pragma unroll
      for (int r = 0; r < 4; ++r) {
        const int q = (w << 5) + (qh << 4) + (g << 2) + r;
        Cb[(size_t)q * DM + d] = f2bf(accc[qh][nf][r] * lr[r]);
      }
    }
  }
}

// ---------------------------------------------------------------------------
extern "C" void kernel_launch(void* const* d_in, const int* in_sizes, int n_in,
                              void* d_out, int out_size, void* d_ws, size_t ws_size,
                              hipStream_t stream) {
  const float* x  = (const float*)d_in[0];
  const float* Wq = (const float*)d_in[1];
  const float* bq = (const float*)d_in[2];
  const float* Wk = (const float*)d_in[3];
  const float* bk = (const float*)d_in[4];
  const float* Wv = (const float*)d_in[5];
  const float* bv = (const float*)d_in[6];
  const float* Wo = (const float*)d_in[7];
  const float* bo = (const float*)d_in[8];

  char* ws = (char*)d_ws;
  size_t off = 0;
  auto alloc = [&](size_t bytes) -> void* {
    void* p = ws + off;
    off += (bytes + 255) & ~(size_t)255;
    return p;
  };
  const size_t XB = (size_t)MT * DM * 2;   // 16.78 MB
  const size_t WB = (size_t)DM * DM * 2;   // 2.10 MB
  unsigned short* Xb  = (unsigned short*)alloc(XB);
  unsigned short* Wqb = (unsigned short*)alloc(WB);
  unsigned short* Wkb = (unsigned short*)alloc(WB);
  unsigned short* Wvb = (unsigned short*)alloc(WB);
  unsigned short* Wob = (unsigned short*)alloc(WB);
  unsigned short* Qb  = (unsigned short*)alloc(XB);
  unsigned short* Kb  = (unsigned short*)alloc(XB);
  unsigned short* Vtb = (unsigned short*)alloc(XB);
  unsigned short* Cxb = (unsigned short*)alloc(XB);

  cast_all_k<<<dim3(1024), dim3(256), 0, stream>>>(
      x, Wq, Wk, Wv, Wo, Xb, Wqb, Wkb, Wvb, Wob);
  qkv_gemm_k<<<dim3(1536), dim3(256), 0, stream>>>(
      Xb, Wqb, Wkb, Wvb, bq, bk, bv, Qb, Kb, Vtb);
  attn_k<<<dim3(1024), dim3(256), 0, stream>>>(Qb, Kb, Vtb, Cxb);
  gemm_o_k<<<dim3(512), dim3(256), 0, stream>>>(Cxb, Wob, bo, (float*)d_out);
}